// Round 7
// baseline (610.485 us; speedup 1.0000x reference)
//
#include <hip/hip_runtime.h>
#include <hip/hip_bf16.h>

// Round 15: mega-kernel retry, hang-proofed.
//   Root cause of R14 container failure: grid sized by occupancy API; if it
//   under-accounts 72KB static LDS it returns 8/CU -> 800 blocks, only 512
//   resident -> barrier deadlock. Fixes:
//   - grid HARD-CODED 512 (2/CU by LDS arithmetic: 144<=160KB, launch_bounds)
//   - bounded barrier spin (~0.8s) -> failure mode is wrong-numerics, not hang
//   - XCD-chunked gemm job mapping (R5's proven L2-resident layout)
//   - phase bodies verbatim from round-5 PASSING kernel

#define B_SZ     4096
#define LSTM_N   400
#define NG       1600   // 4*LSTM
#define VOCAB    73
#define NATTN    10
#define CHARLEN  64
#define KP1      512
#define KP23     896
#define NBLK     512    // 2 blocks/CU x 256 CU; co-residency by construction
#define NJOBS_A  1024   // 4096 / 4

typedef _Float16 half8 __attribute__((ext_vector_type(8)));
typedef __attribute__((ext_vector_type(4))) float floatx4;

__device__ __forceinline__ void gload_lds16(const void* g, void* l) {
    __builtin_amdgcn_global_load_lds(
        (const __attribute__((address_space(1))) void*)g,
        (__attribute__((address_space(3))) void*)l, 16, 0, 0);
}

// [row][64-half] LDS tile, XOR-swizzled 16B granules within each 128B row
__device__ __forceinline__ int lds_off(int r, int g) {
    return (r << 6) + ((((g ^ r) & 7)) << 3);
}

// ---------------------------------------------------------------- barrier
// Block fence (__syncthreads) + AGENT-scope acq_rel counter/flag: standard
// cooperative barrier; happens-before chains make all producer writes visible
// to consumers after the acquire. Spin is BOUNDED so a sizing bug degrades to
// wrong numerics instead of a hung container.
__device__ __forceinline__ void grid_barrier(int* bar, int phase, int nblk) {
    __syncthreads();
    if (threadIdx.x == 0) {
        int* cnt = bar + phase * 64;
        int* flg = cnt + 32;
        int prev = __hip_atomic_fetch_add(cnt, 1, __ATOMIC_ACQ_REL,
                                          __HIP_MEMORY_SCOPE_AGENT);
        if (prev == nblk - 1) {
            __hip_atomic_store(flg, 1, __ATOMIC_RELEASE,
                               __HIP_MEMORY_SCOPE_AGENT);
        } else {
            int spins = 0;
            while (__hip_atomic_load(flg, __ATOMIC_ACQUIRE,
                                     __HIP_MEMORY_SCOPE_AGENT) == 0) {
                __builtin_amdgcn_s_sleep(8);
                if (++spins > 3000000) break;   // ~0.8s cap: no container hang
            }
        }
    }
    __syncthreads();
}

// ---------------------------------------------------------------- pack chunk
// Layouts:
//   X1 (KP1):  [w_prev 0..73 | inputs 73..76 | h1 76..476 | 0pad]
//   XA (KP1):  [h1n 0..400 | w_prev 400..473 | inputs 473..476 | 0pad]
//   X2 (KP23): [h1n 0..400 | inputs 400..403 | w 403..476 | h2 476..876 | 0pad]
//   X3 (KP23): [h2n 0..400 | inputs 400..403 | w 403..476 | h3 476..876 | 0pad]
// W rows: n = 4u+g <- src row g*400+u.
#define CW1   102400            // 1600 * 64
#define CW23  179200            // 1600 * 112
#define CWA   4096              // 64 * 64
#define CX1   262144            // 4096 * 64
#define CXA   57344             // 4096 * 14   (cols 400..512)
#define CX23  253952            // 4096 * 62   (cols 400..896, both X2 & X3)
#define O1    (CW1)
#define O2    (O1 + CW23)
#define O3    (O2 + CW23)
#define O4    (O3 + CWA)
#define O5    (O4 + CX1)
#define O6    (O5 + CXA)
#define O7    (O6 + CX23)       // 1038336 = 256 * 4056
#define NCHUNK (O7 / 256)       // 4056

__device__ __forceinline__ void pack_chunk(int id,
    const float* __restrict__ Wih1, const float* __restrict__ Whh1,
    const float* __restrict__ Wih2, const float* __restrict__ Whh2,
    const float* __restrict__ Wih3, const float* __restrict__ Whh3,
    const float* __restrict__ W_attn,
    const float* __restrict__ w_prev, const float* __restrict__ inputs,
    const float* __restrict__ h1, const float* __restrict__ h2,
    const float* __restrict__ h3,
    _Float16* __restrict__ W1, _Float16* __restrict__ W2,
    _Float16* __restrict__ W3, _Float16* __restrict__ Wa,
    _Float16* __restrict__ X1, _Float16* __restrict__ XA,
    _Float16* __restrict__ X2, _Float16* __restrict__ X3)
{
    half8 hv;
    if (id < O1) {                       // ---- W1: 1600 x 512
        const int row = id >> 6;
        const int k0  = (id & 63) << 3;
        const int u = row >> 2, g = row & 3;
        const int src = g * 400 + u;
#pragma unroll
        for (int e = 0; e < 8; e++) {
            const int k = k0 + e;
            float x = 0.f;
            if (k < 76)           x = Wih1[(size_t)src * 76 + k];
            else if (k < 476)     x = Whh1[(size_t)src * 400 + (k - 76)];
            hv[e] = (_Float16)x;
        }
        *(half8*)(W1 + (size_t)row * KP1 + k0) = hv;
    } else if (id < O3) {                // ---- W2 / W3: 1600 x 896
        const int id2 = id - O1;
        const bool is3 = (id2 >= CW23);
        const int id3 = is3 ? id2 - CW23 : id2;
        const int row = id3 / 112;
        const int k0  = (id3 - row * 112) << 3;
        const int u = row >> 2, g = row & 3;
        const int src = g * 400 + u;
        const float* Wih = is3 ? Wih3 : Wih2;
        const float* Whh = is3 ? Whh3 : Whh2;
#pragma unroll
        for (int e = 0; e < 8; e++) {
            const int k = k0 + e;
            float x = 0.f;
            if (k < 400)          x = Wih[(size_t)src * 476 + 3 + k];
            else if (k < 403)     x = Wih[(size_t)src * 476 + (k - 400)];
            else if (k < 476)     x = Wih[(size_t)src * 476 + k];
            else if (k < 876)     x = Whh[(size_t)src * 400 + (k - 476)];
            hv[e] = (_Float16)x;
        }
        *(half8*)((is3 ? W3 : W2) + (size_t)row * KP23 + k0) = hv;
    } else if (id < O4) {                // ---- Wa: 64 x 512 (rows >=30 zero)
        const int id4 = id - O3;
        const int row = id4 >> 6;
        const int k0  = (id4 & 63) << 3;
#pragma unroll
        for (int e = 0; e < 8; e++) {
            const int k = k0 + e;
            float x = 0.f;
            if (row < 30) {
                if (k < 400)      x = W_attn[(size_t)row * 476 + 76 + k];
                else if (k < 473) x = W_attn[(size_t)row * 476 + (k - 400)];
                else if (k < 476) x = W_attn[(size_t)row * 476 + 73 + (k - 473)];
            }
            hv[e] = (_Float16)x;
        }
        *(half8*)(Wa + (size_t)row * KP1 + k0) = hv;
    } else if (id < O5) {                // ---- X1: 4096 x 512
        const int id5 = id - O4;
        const int b  = id5 >> 6;
        const int k0 = (id5 & 63) << 3;
#pragma unroll
        for (int e = 0; e < 8; e++) {
            const int k = k0 + e;
            float x = 0.f;
            if (k < 73)           x = w_prev[(size_t)b * 73 + k];
            else if (k < 76)      x = inputs[(size_t)b * 3 + (k - 73)];
            else if (k < 476)     x = h1[(size_t)b * 400 + (k - 76)];
            hv[e] = (_Float16)x;
        }
        *(half8*)(X1 + (size_t)b * KP1 + k0) = hv;
    } else if (id < O6) {                // ---- XA cols 400..512
        const int id6 = id - O5;
        const int b  = id6 / 14;
        const int k0 = 400 + ((id6 - b * 14) << 3);
#pragma unroll
        for (int e = 0; e < 8; e++) {
            const int k = k0 + e;
            float x = 0.f;
            if (k < 473)          x = w_prev[(size_t)b * 73 + (k - 400)];
            else if (k < 476)     x = inputs[(size_t)b * 3 + (k - 473)];
            hv[e] = (_Float16)x;
        }
        *(half8*)(XA + (size_t)b * KP1 + k0) = hv;
    } else {                             // ---- X2+X3 cols 400..896
        const int id7 = id - O6;
        const int b  = id7 / 62;
        const int k0 = 400 + ((id7 - b * 62) << 3);
        half8 h2v, h3v;
#pragma unroll
        for (int e = 0; e < 8; e++) {
            const int k = k0 + e;
            float x2 = 0.f, x3 = 0.f;
            if (k < 403)                    { x2 = inputs[(size_t)b * 3 + (k - 400)]; x3 = x2; }
            else if (k >= 476 && k < 876)   { x2 = h2[(size_t)b * 400 + (k - 476)];
                                              x3 = h3[(size_t)b * 400 + (k - 476)]; }
            h2v[e] = (_Float16)x2;
            h3v[e] = (_Float16)x3;
        }
        *(half8*)(X2 + (size_t)b * KP23 + k0) = h2v;
        *(half8*)(X3 + (size_t)b * KP23 + k0) = h3v;
    }
}

// ---------------------------------------------------------------- gemm job
// 64x128 tile, 4 waves (2x2), each wave 32x64 = 2x4 frags. BK=64.
// 3 LDS buffers, depth-2 prefetch, steady-state vmcnt(12). (R5 body.)
template<int KP>
__device__ __forceinline__ void gemm_job(int job, _Float16 (*lds)[192 * 64],
    const _Float16* __restrict__ Wm, const _Float16* __restrict__ X,
    const float* __restrict__ bias, const float* __restrict__ c_in,
    _Float16* __restrict__ d1, int ld1,
    _Float16* __restrict__ d2, int ld2, float* __restrict__ fout)
{
    const int t    = threadIdx.x;
    const int w    = t >> 6;
    const int lane = t & 63;
    const int quad = lane >> 4;
    const int l16  = lane & 15;
    const int by   = job % 25;              // row tile
    const int bx   = job / 25;              // batch tile
    const int m0   = by * 64;
    const int n0   = bx * 128;
    const int wm   = (w >> 1) * 32;
    const int wn   = (w & 1) * 64;
    const int lr   = lane >> 3;
    const int gq   = (lane & 7) ^ lr;

    floatx4 acc[2][4] = {};

    auto stage = [&](int sb, int k0) {
#pragma unroll
        for (int s = 0; s < 2; s++)
            gload_lds16(Wm + (size_t)(m0 + w * 16 + s * 8 + lr) * KP + k0 + gq * 8,
                        &lds[sb][(w * 16 + s * 8) * 64]);
#pragma unroll
        for (int s = 0; s < 4; s++)
            gload_lds16(X + (size_t)(n0 + w * 32 + s * 8 + lr) * KP + k0 + gq * 8,
                        &lds[sb][(64 + w * 32 + s * 8) * 64]);
    };

    stage(0, 0);
    stage(1, 64);
    constexpr int NT = KP / 64;
#pragma unroll
    for (int kt = 0; kt < NT; kt++) {
        const int sb = kt % 3;
        if (kt + 2 < NT) {
            stage((kt + 2) % 3, (kt + 2) * 64);
            asm volatile("s_waitcnt vmcnt(12)" ::: "memory");
        } else if (kt + 1 < NT) {
            asm volatile("s_waitcnt vmcnt(6)" ::: "memory");
        } else {
            asm volatile("s_waitcnt vmcnt(0)" ::: "memory");
        }
        __builtin_amdgcn_s_barrier();
        __builtin_amdgcn_sched_barrier(0);

#pragma unroll
        for (int h = 0; h < 2; h++) {
            half8 af[2], bf[4];
#pragma unroll
            for (int i = 0; i < 2; i++)
                af[i] = *(const half8*)(&lds[sb][lds_off(wm + i * 16 + l16, h * 4 + quad)]);
#pragma unroll
            for (int i = 0; i < 4; i++)
                bf[i] = *(const half8*)(&lds[sb][lds_off(64 + wn + i * 16 + l16, h * 4 + quad)]);
            __builtin_amdgcn_s_setprio(1);
#pragma unroll
            for (int mt = 0; mt < 2; mt++)
#pragma unroll
                for (int nt = 0; nt < 4; nt++)
                    acc[mt][nt] = __builtin_amdgcn_mfma_f32_16x16x32_f16(
                        af[mt], bf[nt], acc[mt][nt], 0, 0, 0);
            __builtin_amdgcn_s_setprio(0);
        }
        __builtin_amdgcn_s_barrier();
    }
    __builtin_amdgcn_sched_barrier(0);

    // epilogue: descattered I/O via LDS transpose
    const int u0 = m0 >> 2;
    float*    Cs   = (float*)&lds[0][0];
    _Float16* Hs16 = (_Float16*)&lds[1][0];
    float*    Hs32 = (float*)&lds[1][0];
    {
        const int bl = t >> 1;
        const int j0 = (t & 1) * 2;
#pragma unroll
        for (int j = 0; j < 2; j++) {
            floatx4 cv = *(const floatx4*)(c_in + (size_t)(n0 + bl) * LSTM_N
                                           + u0 + (j0 + j) * 4);
            *(floatx4*)(Cs + bl * 20 + (j0 + j) * 4) = cv;
        }
    }
    __syncthreads();

#pragma unroll
    for (int mt = 0; mt < 2; mt++) {
        const int ul = (wm >> 2) + mt * 4 + quad;
        const int u  = u0 + ul;
        const float bi  = bias[u];
        const float bff = bias[400 + u];
        const float bg  = bias[800 + u];
        const float bo  = bias[1200 + u];
#pragma unroll
        for (int nt = 0; nt < 4; nt++) {
            const int bl = wn + nt * 16 + l16;
            float gi = acc[mt][nt][0] + bi;
            float gf = acc[mt][nt][1] + bff;
            float gg = acc[mt][nt][2] + bg;
            float go = acc[mt][nt][3] + bo;
            float si = 1.f / (1.f + expf(-gi));
            float sf = 1.f / (1.f + expf(-gf));
            float so = 1.f / (1.f + expf(-go));
            float cn = sf * Cs[bl * 20 + ul] + si * tanhf(gg);
            float h  = so * tanhf(cn);
            if (fout) Hs32[bl * 20 + ul] = h;
            else      Hs16[bl * 24 + ul] = (_Float16)h;
        }
    }
    __syncthreads();

    if (fout) {
        const int bl = t >> 1;
        const int p0 = (t & 1) * 2;
#pragma unroll
        for (int j = 0; j < 2; j++) {
            floatx4 hvv = *(const floatx4*)(Hs32 + bl * 20 + (p0 + j) * 4);
            *(floatx4*)(fout + (size_t)(n0 + bl) * LSTM_N + u0 + (p0 + j) * 4) = hvv;
        }
    } else {
        const int bl = t >> 1;
        const int p  = t & 1;
        half8 hvv = *(const half8*)(Hs16 + bl * 24 + p * 8);
        *(half8*)(d1 + (size_t)(n0 + bl) * ld1 + u0 + p * 8) = hvv;
        if (d2) *(half8*)(d2 + (size_t)(n0 + bl) * ld2 + u0 + p * 8) = hvv;
    }
    __syncthreads();    // LDS safe for next job
}

// Per-block job iteration, XCD-chunked: blocks round-robin XCDs by bid&7;
// each XCD's 64 blocks own a contiguous 100-job chunk (4 batch-tiles x 25
// row-tiles -> W 2.9MB + X-slice 0.9MB < 4MB per-XCD L2).
template<int KP>
__device__ __forceinline__ void gemm_phase(int bid, _Float16 (*lds)[192 * 64],
    const _Float16* __restrict__ Wm, const _Float16* __restrict__ X,
    const float* __restrict__ bias, const float* __restrict__ c_in,
    _Float16* __restrict__ d1, int ld1,
    _Float16* __restrict__ d2, int ld2, float* __restrict__ fout)
{
    const int xcd = bid & 7;
    const int wi  = bid >> 3;               // 0..63 within XCD
    for (int j = wi; j < 100; j += 64)
        gemm_job<KP>(xcd * 100 + j, lds, Wm, X, bias, c_in, d1, ld1, d2, ld2, fout);
}

// ---------------------------------------------------------------- attn job
// job = 4 batch rows (one per wave). Wa staged in LDS, wave dot-products,
// softplus, phi, einsum -> w into X2/X3. (R5 body.)
__device__ __forceinline__ void attn_job(int job, _Float16* smem,
    const _Float16* __restrict__ Wa, const _Float16* __restrict__ XA,
    const float* __restrict__ b_attn, const float* __restrict__ kappa,
    const float* __restrict__ AV, const int* __restrict__ alen,
    _Float16* __restrict__ X2, _Float16* __restrict__ X3)
{
    _Float16* Wa_s = smem;                        // 30 KB
    float* prm   = (float*)(smem + 30 * KP1);     // [4][32]
    float* phi_s = prm + 128;                     // [4][64]

    const int t = threadIdx.x;
#pragma unroll
    for (int i = 0; i < 8; i++) {
        const int idx = t + i * 256;
        if (idx < 1920) {
            const int row = idx >> 6;
            const int c8  = (idx & 63) << 3;
            *(half8*)(&Wa_s[row * KP1 + c8]) = *(const half8*)(Wa + (size_t)row * KP1 + c8);
        }
    }
    __syncthreads();

    const int wave = t >> 6;
    const int lane = t & 63;
    const int b = job * 4 + wave;

    half8 xa = *(const half8*)(XA + (size_t)b * KP1 + lane * 8);
    float xf[8];
#pragma unroll
    for (int e = 0; e < 8; e++) xf[e] = (float)xa[e];

    float myp = 0.f;
#pragma unroll
    for (int m = 0; m < 30; m++) {
        half8 wv = *(const half8*)(&Wa_s[m * KP1 + lane * 8]);
        float s = 0.f;
#pragma unroll
        for (int e = 0; e < 8; e++) s += (float)wv[e] * xf[e];
#pragma unroll
        for (int sh = 32; sh >= 1; sh >>= 1) s += __shfl_xor(s, sh, 64);
        if (lane == m) myp = s;
    }

    if (lane < 30) {
        float p  = myp + b_attn[lane];
        float sp = (p > 20.f) ? p : log1pf(expf(p));
        float v;
        if (lane < 10)      v = sp;
        else if (lane < 20) v = fmaxf(sp, 0.01f);
        else                v = kappa[(size_t)b * NATTN + (lane - 20)] + sp * (1.f / 25.f);
        prm[wave * 32 + lane] = v;
    }
    __syncthreads();

    const int len = alen[b];
    {
        int c = lane;
        float phi = 0.f;
#pragma unroll
        for (int j = 0; j < NATTN; j++) {
            float d = prm[wave * 32 + 20 + j] - (float)c;
            phi += prm[wave * 32 + j] * expf(-d * d / prm[wave * 32 + 10 + j]);
        }
        phi_s[wave * 64 + c] = (c < len) ? phi : 0.f;
    }
    __syncthreads();

    for (int v0 = 0; v0 < VOCAB; v0 += 64) {
        const int v = v0 + lane;
        if (v < VOCAB) {
            const float* avb = AV + (size_t)b * CHARLEN * VOCAB + v;
            float s = 0.f;
            for (int c = 0; c < len; c++)
                s += phi_s[wave * 64 + c] * avb[(size_t)c * VOCAB];
            _Float16 wv = (_Float16)s;
            X2[(size_t)b * KP23 + 403 + v] = wv;
            X3[(size_t)b * KP23 + 403 + v] = wv;
        }
    }
    __syncthreads();    // LDS safe for next job
}

// ---------------------------------------------------------------- mega
__global__ __launch_bounds__(256, 2) void mega(
    const float* Wih1, const float* Whh1, const float* Wih2, const float* Whh2,
    const float* Wih3, const float* Whh3, const float* W_attn,
    const float* w_prev, const float* inputs,
    const float* h1, const float* h2, const float* h3,
    const float* c1, const float* c2, const float* c3,
    const float* b1, const float* b_attn, const float* b2, const float* b3,
    const float* kappa, const float* AV, const int* alen,
    _Float16* W1, _Float16* W2, _Float16* W3, _Float16* Wa,
    _Float16* X1, _Float16* XA, _Float16* X2, _Float16* X3,
    float* out, int* bar)
{
    __shared__ _Float16 lds[3][192 * 64];   // 72 KB -> 2 blocks/CU (144<=160)

    const int bid = blockIdx.x;

    // phase 0: pack everything
    for (int c = bid; c < NCHUNK; c += NBLK)
        pack_chunk(c * 256 + threadIdx.x, Wih1, Whh1, Wih2, Whh2, Wih3, Whh3,
                   W_attn, w_prev, inputs, h1, h2, h3,
                   W1, W2, W3, Wa, X1, XA, X2, X3);
    grid_barrier(bar, 0, NBLK);

    // phase 1: LSTM1 -> h1n into XA col0 + X2 col0
    gemm_phase<KP1>(bid, lds, W1, X1, b1, c1, XA, KP1, X2, KP23, nullptr);
    grid_barrier(bar, 1, NBLK);

    // phase 2: attention -> w into X2/X3 cols 403..476 (2 jobs/block exactly)
    for (int job = bid; job < NJOBS_A; job += NBLK)
        attn_job(job, &lds[0][0], Wa, XA, b_attn, kappa, AV, alen, X2, X3);
    grid_barrier(bar, 2, NBLK);

    // phase 3: LSTM2 -> h2n into X3 col0
    gemm_phase<KP23>(bid, lds, W2, X2, b2, c2, X3, KP23, nullptr, 0, nullptr);
    grid_barrier(bar, 3, NBLK);

    // phase 4: LSTM3 -> out (fp32)
    gemm_phase<KP23>(bid, lds, W3, X3, b3, c3, nullptr, 0, nullptr, 0, out);
}

// ---------------------------------------------------------------- launch
extern "C" void kernel_launch(void* const* d_in, const int* in_sizes, int n_in,
                              void* d_out, int out_size, void* d_ws, size_t ws_size,
                              hipStream_t stream)
{
    const float* inputs = (const float*)d_in[0];
    const float* h1     = (const float*)d_in[1];
    const float* c1     = (const float*)d_in[2];
    const float* h2     = (const float*)d_in[3];
    const float* c2     = (const float*)d_in[4];
    const float* h3     = (const float*)d_in[5];
    const float* c3     = (const float*)d_in[6];
    const float* kappa  = (const float*)d_in[7];
    const float* w_prev = (const float*)d_in[8];
    const float* AV     = (const float*)d_in[9];
    const int*   alen   = (const int*)d_in[10];
    const float* W_ih1  = (const float*)d_in[11];
    const float* W_hh1  = (const float*)d_in[12];
    const float* b1     = (const float*)d_in[13];
    const float* W_attn = (const float*)d_in[14];
    const float* b_attn = (const float*)d_in[15];
    const float* W_ih2  = (const float*)d_in[16];
    const float* W_hh2  = (const float*)d_in[17];
    const float* b2     = (const float*)d_in[18];
    const float* W_ih3  = (const float*)d_in[19];
    const float* W_hh3  = (const float*)d_in[20];
    const float* b3     = (const float*)d_in[21];
    float* out = (float*)d_out;

    char* p = (char*)d_ws;
    _Float16* X1 = (_Float16*)p; p += (size_t)B_SZ * KP1 * 2;
    _Float16* XA = (_Float16*)p; p += (size_t)B_SZ * KP1 * 2;
    _Float16* X2 = (_Float16*)p; p += (size_t)B_SZ * KP23 * 2;
    _Float16* X3 = (_Float16*)p; p += (size_t)B_SZ * KP23 * 2;
    _Float16* W1 = (_Float16*)p; p += (size_t)NG * KP1 * 2;
    _Float16* W2 = (_Float16*)p; p += (size_t)NG * KP23 * 2;
    _Float16* W3 = (_Float16*)p; p += (size_t)NG * KP23 * 2;
    _Float16* Wa = (_Float16*)p; p += (size_t)64 * KP1 * 2;
    int* bar = (int*)p;                     // 4 phases x 256 B

    hipMemsetAsync(bar, 0, 1024, stream);
    mega<<<NBLK, 256, 0, stream>>>(W_ih1, W_hh1, W_ih2, W_hh2, W_ih3, W_hh3,
                                   W_attn, w_prev, inputs, h1, h2, h3,
                                   c1, c2, c3, b1, b_attn, b2, b3,
                                   kappa, AV, alen,
                                   W1, W2, W3, Wa, X1, XA, X2, X3,
                                   out, bar);
}

// Round 8
// 281.952 us; speedup vs baseline: 2.1652x; 2.1652x over previous
//
#include <hip/hip_runtime.h>
#include <hip/hip_bf16.h>

// Round 16: back to the 5-kernel chain (mega refuted: 490us vs sum ~170;
// wall-minus-kernels ~120us is FIXED harness overhead, dispatch-count-
// independent). Attack the remaining GEMM latency with TLP:
//   - 64x256 tile, 512 thr = 8 waves (2m x 4n of 32x64), dbuf 2x40KB = 80KB
//     -> 2 blocks/CU = 16 waves/CU (4/SIMD, 2x all prior rounds)
//   - staging 269 -> 224 MB; counted vmcnt(5) (5 loads/thread/K-step)
//   - 400 blocks = 8 XCD x (2 batch-tiles x 25 row-tiles), W+X-slice < 4MB L2
//   - pack_all / attn_fused verbatim from round-5 passing kernel

#define B_SZ     4096
#define LSTM_N   400
#define NG       1600   // 4*LSTM
#define VOCAB    73
#define NATTN    10
#define CHARLEN  64
#define KP1      512
#define KP23     896

typedef _Float16 half8 __attribute__((ext_vector_type(8)));
typedef __attribute__((ext_vector_type(4))) float floatx4;

__device__ __forceinline__ void gload_lds16(const void* g, void* l) {
    __builtin_amdgcn_global_load_lds(
        (const __attribute__((address_space(1))) void*)g,
        (__attribute__((address_space(3))) void*)l, 16, 0, 0);
}

// [row][64-half] LDS tile, XOR-swizzled 16B granules within each 128B row
__device__ __forceinline__ int lds_off(int r, int g) {
    return (r << 6) + ((((g ^ r) & 7)) << 3);
}

// ---------------------------------------------------------------- pack (all)
// Layouts:
//   X1 (KP1):  [w_prev 0..73 | inputs 73..76 | h1 76..476 | 0pad]
//   XA (KP1):  [h1n 0..400 | w_prev 400..473 | inputs 473..476 | 0pad]
//   X2 (KP23): [h1n 0..400 | inputs 400..403 | w 403..476 | h2 476..876 | 0pad]
//   X3 (KP23): [h2n 0..400 | inputs 400..403 | w 403..476 | h3 476..876 | 0pad]
// W rows: n = 4u+g <- src row g*400+u.
#define CW1   102400            // 1600 * 64
#define CW23  179200            // 1600 * 112
#define CWA   4096              // 64 * 64
#define CX1   262144            // 4096 * 64
#define CXA   57344             // 4096 * 14   (cols 400..512)
#define CX23  253952            // 4096 * 62   (cols 400..896, both X2 & X3)
#define O1    (CW1)
#define O2    (O1 + CW23)
#define O3    (O2 + CW23)
#define O4    (O3 + CWA)
#define O5    (O4 + CX1)
#define O6    (O5 + CXA)
#define O7    (O6 + CX23)       // 1038336 = 256 * 4056

__global__ __launch_bounds__(256) void pack_all(const float* __restrict__ Wih1,
                                                const float* __restrict__ Whh1,
                                                const float* __restrict__ Wih2,
                                                const float* __restrict__ Whh2,
                                                const float* __restrict__ Wih3,
                                                const float* __restrict__ Whh3,
                                                const float* __restrict__ W_attn,
                                                const float* __restrict__ w_prev,
                                                const float* __restrict__ inputs,
                                                const float* __restrict__ h1,
                                                const float* __restrict__ h2,
                                                const float* __restrict__ h3,
                                                _Float16* __restrict__ W1,
                                                _Float16* __restrict__ W2,
                                                _Float16* __restrict__ W3,
                                                _Float16* __restrict__ Wa,
                                                _Float16* __restrict__ X1,
                                                _Float16* __restrict__ XA,
                                                _Float16* __restrict__ X2,
                                                _Float16* __restrict__ X3)
{
    const int id = blockIdx.x * 256 + threadIdx.x;
    half8 hv;

    if (id < O1) {                       // ---- W1: 1600 x 512
        const int row = id >> 6;
        const int k0  = (id & 63) << 3;
        const int u = row >> 2, g = row & 3;
        const int src = g * 400 + u;
#pragma unroll
        for (int e = 0; e < 8; e++) {
            const int k = k0 + e;
            float x = 0.f;
            if (k < 76)           x = Wih1[(size_t)src * 76 + k];
            else if (k < 476)     x = Whh1[(size_t)src * 400 + (k - 76)];
            hv[e] = (_Float16)x;
        }
        *(half8*)(W1 + (size_t)row * KP1 + k0) = hv;
    } else if (id < O3) {                // ---- W2 / W3: 1600 x 896
        const int id2 = id - O1;
        const bool is3 = (id2 >= CW23);
        const int id3 = is3 ? id2 - CW23 : id2;
        const int row = id3 / 112;
        const int k0  = (id3 - row * 112) << 3;
        const int u = row >> 2, g = row & 3;
        const int src = g * 400 + u;
        const float* Wih = is3 ? Wih3 : Wih2;
        const float* Whh = is3 ? Whh3 : Whh2;
#pragma unroll
        for (int e = 0; e < 8; e++) {
            const int k = k0 + e;
            float x = 0.f;
            if (k < 400)          x = Wih[(size_t)src * 476 + 3 + k];
            else if (k < 403)     x = Wih[(size_t)src * 476 + (k - 400)];
            else if (k < 476)     x = Wih[(size_t)src * 476 + k];
            else if (k < 876)     x = Whh[(size_t)src * 400 + (k - 476)];
            hv[e] = (_Float16)x;
        }
        *(half8*)((is3 ? W3 : W2) + (size_t)row * KP23 + k0) = hv;
    } else if (id < O4) {                // ---- Wa: 64 x 512 (rows >=30 zero)
        const int id4 = id - O3;
        const int row = id4 >> 6;
        const int k0  = (id4 & 63) << 3;
#pragma unroll
        for (int e = 0; e < 8; e++) {
            const int k = k0 + e;
            float x = 0.f;
            if (row < 30) {
                if (k < 400)      x = W_attn[(size_t)row * 476 + 76 + k];
                else if (k < 473) x = W_attn[(size_t)row * 476 + (k - 400)];
                else if (k < 476) x = W_attn[(size_t)row * 476 + 73 + (k - 473)];
            }
            hv[e] = (_Float16)x;
        }
        *(half8*)(Wa + (size_t)row * KP1 + k0) = hv;
    } else if (id < O5) {                // ---- X1: 4096 x 512
        const int id5 = id - O4;
        const int b  = id5 >> 6;
        const int k0 = (id5 & 63) << 3;
#pragma unroll
        for (int e = 0; e < 8; e++) {
            const int k = k0 + e;
            float x = 0.f;
            if (k < 73)           x = w_prev[(size_t)b * 73 + k];
            else if (k < 76)      x = inputs[(size_t)b * 3 + (k - 73)];
            else if (k < 476)     x = h1[(size_t)b * 400 + (k - 76)];
            hv[e] = (_Float16)x;
        }
        *(half8*)(X1 + (size_t)b * KP1 + k0) = hv;
    } else if (id < O6) {                // ---- XA cols 400..512
        const int id6 = id - O5;
        const int b  = id6 / 14;
        const int k0 = 400 + ((id6 - b * 14) << 3);
#pragma unroll
        for (int e = 0; e < 8; e++) {
            const int k = k0 + e;
            float x = 0.f;
            if (k < 473)          x = w_prev[(size_t)b * 73 + (k - 400)];
            else if (k < 476)     x = inputs[(size_t)b * 3 + (k - 473)];
            hv[e] = (_Float16)x;
        }
        *(half8*)(XA + (size_t)b * KP1 + k0) = hv;
    } else if (id < O7) {                // ---- X2+X3 cols 400..896
        const int id7 = id - O6;
        const int b  = id7 / 62;
        const int k0 = 400 + ((id7 - b * 62) << 3);
        half8 h2v, h3v;
#pragma unroll
        for (int e = 0; e < 8; e++) {
            const int k = k0 + e;
            float x2 = 0.f, x3 = 0.f;
            if (k < 403)                    { x2 = inputs[(size_t)b * 3 + (k - 400)]; x3 = x2; }
            else if (k >= 476 && k < 876)   { x2 = h2[(size_t)b * 400 + (k - 476)];
                                              x3 = h3[(size_t)b * 400 + (k - 476)]; }
            h2v[e] = (_Float16)x2;
            h3v[e] = (_Float16)x3;
        }
        *(half8*)(X2 + (size_t)b * KP23 + k0) = h2v;
        *(half8*)(X3 + (size_t)b * KP23 + k0) = h3v;
    }
}

// ---------------------------------------------------------------- fused GEMM
// 64(rows) x 256(batch) tile, BK=64, 512 thr = 8 waves (2m x 4n), each wave
// 32x64 = 2x4 frags. Dbuf 2x40KB = 80KB -> 2 blocks/CU = 16 waves/CU
// (4 waves/SIMD TLP). Counted vmcnt(5). 400 blocks = 8 XCD x 50.
template<int KP>
__global__ __launch_bounds__(512, 4) void gemm_fused_t(const _Float16* __restrict__ Wm,
                                                       const _Float16* __restrict__ X,
                                                       const float* __restrict__ bias,
                                                       const float* __restrict__ c_in,
                                                       _Float16* __restrict__ d1, int ld1,
                                                       _Float16* __restrict__ d2, int ld2,
                                                       float* __restrict__ fout)
{
    __shared__ _Float16 lds[2][320 * 64];   // [A 64 rows | B 256 rows] x2 = 80KB

    const int t    = threadIdx.x;
    const int w    = t >> 6;                // 0..7
    const int lane = t & 63;
    const int quad = lane >> 4;
    const int l16  = lane & 15;
    // bijective XCD chunks: 400 = 8 x 50; each XCD: 2 batch-tiles x 25 rows
    const int fid  = blockIdx.y * 16 + blockIdx.x;
    const int xcd  = fid & 7;
    const int loc  = fid >> 3;              // 0..49
    const int bx   = xcd * 2 + loc / 25;    // batch tile 0..15
    const int by   = loc % 25;              // row tile 0..24
    const int m0   = by * 64;
    const int n0   = bx * 256;
    const int wm   = (w >> 2) * 32;         // 0 or 32
    const int wn   = (w & 3) * 64;          // 0..192
    const int lr   = lane >> 3;             // 0..7 row-in-8
    const int gq   = (lane & 7) ^ lr;       // granule this lane fetches

    floatx4 acc[2][4] = {};

    // 5 global_load_lds per thread per K-step (1 W + 4 X)
    auto stage = [&](int sb, int k0) {
        gload_lds16(Wm + (size_t)(m0 + w * 8 + lr) * KP + k0 + gq * 8,
                    &lds[sb][(w * 8) * 64]);
#pragma unroll
        for (int s = 0; s < 4; s++)
            gload_lds16(X + (size_t)(n0 + w * 32 + s * 8 + lr) * KP + k0 + gq * 8,
                        &lds[sb][(64 + w * 32 + s * 8) * 64]);
    };

    stage(0, 0);
    constexpr int NT = KP / 64;
#pragma unroll
    for (int kt = 0; kt < NT; kt++) {
        const int sb = kt & 1;
        if (kt + 1 < NT) {
            stage(sb ^ 1, (kt + 1) * 64);
            asm volatile("s_waitcnt vmcnt(5)" ::: "memory");   // this tile done
        } else {
            asm volatile("s_waitcnt vmcnt(0)" ::: "memory");
        }
        __builtin_amdgcn_s_barrier();
        __builtin_amdgcn_sched_barrier(0);

#pragma unroll
        for (int h = 0; h < 2; h++) {
            half8 af[2], bf[4];
#pragma unroll
            for (int i = 0; i < 2; i++)
                af[i] = *(const half8*)(&lds[sb][lds_off(wm + i * 16 + l16, h * 4 + quad)]);
#pragma unroll
            for (int i = 0; i < 4; i++)
                bf[i] = *(const half8*)(&lds[sb][lds_off(64 + wn + i * 16 + l16, h * 4 + quad)]);
            __builtin_amdgcn_s_setprio(1);
#pragma unroll
            for (int mt = 0; mt < 2; mt++)
#pragma unroll
                for (int nt = 0; nt < 4; nt++)
                    acc[mt][nt] = __builtin_amdgcn_mfma_f32_16x16x32_f16(
                        af[mt], bf[nt], acc[mt][nt], 0, 0, 0);
            __builtin_amdgcn_s_setprio(0);
        }
        __builtin_amdgcn_s_barrier();
    }
    __builtin_amdgcn_sched_barrier(0);

    // ---------------- epilogue: descattered I/O via LDS transpose ----------
    const int u0 = m0 >> 2;                   // first unit of this block (x16)
    float*    Cs   = (float*)&lds[0][0];      // [256][20] f32 (20KB)
    _Float16* Hs16 = (_Float16*)&lds[1][0];   // [256][24] f16 (12KB)
    float*    Hs32 = (float*)&lds[1][0];      // [256][20] f32 (20KB)
    {   // stage c tile: 2 thr/row, 2 float4 each (16 units)
        const int bl = t >> 1;
        const int j0 = (t & 1) * 2;
#pragma unroll
        for (int j = 0; j < 2; j++) {
            floatx4 cv = *(const floatx4*)(c_in + (size_t)(n0 + bl) * LSTM_N
                                           + u0 + (j0 + j) * 4);
            *(floatx4*)(Cs + bl * 20 + (j0 + j) * 4) = cv;
        }
    }
    __syncthreads();

#pragma unroll
    for (int mt = 0; mt < 2; mt++) {
        const int ul = (wm >> 2) + mt * 4 + quad;   // 0..15 local unit
        const int u  = u0 + ul;
        const float bi  = bias[u];
        const float bff = bias[400 + u];
        const float bg  = bias[800 + u];
        const float bo  = bias[1200 + u];
#pragma unroll
        for (int nt = 0; nt < 4; nt++) {
            const int bl = wn + nt * 16 + l16;      // local batch 0..255
            float gi = acc[mt][nt][0] + bi;
            float gf = acc[mt][nt][1] + bff;
            float gg = acc[mt][nt][2] + bg;
            float go = acc[mt][nt][3] + bo;
            float si = 1.f / (1.f + expf(-gi));
            float sf = 1.f / (1.f + expf(-gf));
            float so = 1.f / (1.f + expf(-go));
            float cn = sf * Cs[bl * 20 + ul] + si * tanhf(gg);
            float h  = so * tanhf(cn);
            if (fout) Hs32[bl * 20 + ul] = h;
            else      Hs16[bl * 24 + ul] = (_Float16)h;
        }
    }
    __syncthreads();

    if (fout) {   // fp32 out: 64B per batch row, 2 thr/row x 2 float4
        const int bl = t >> 1;
        const int p0 = (t & 1) * 2;
#pragma unroll
        for (int j = 0; j < 2; j++) {
            floatx4 hvv = *(const floatx4*)(Hs32 + bl * 20 + (p0 + j) * 4);
            *(floatx4*)(fout + (size_t)(n0 + bl) * LSTM_N + u0 + (p0 + j) * 4) = hvv;
        }
    } else {      // fp16: 2 thr/row x 1 half8 per dest
        const int bl = t >> 1;
        const int p  = t & 1;
        half8 hvv = *(const half8*)(Hs16 + bl * 24 + p * 8);
        *(half8*)(d1 + (size_t)(n0 + bl) * ld1 + u0 + p * 8) = hvv;
        if (d2) *(half8*)(d2 + (size_t)(n0 + bl) * ld2 + u0 + p * 8) = hvv;
    }
}

// ---------------------------------------------------------------- attn (fused)
// wave = one batch row; 4 waves/block; grid B/4. (R5 body, unchanged.)
__global__ __launch_bounds__(256) void attn_fused(const _Float16* __restrict__ Wa,
                                                  const _Float16* __restrict__ XA,
                                                  const float* __restrict__ b_attn,
                                                  const float* __restrict__ kappa,
                                                  const float* __restrict__ AV,
                                                  const int* __restrict__ alen,
                                                  _Float16* __restrict__ X2,
                                                  _Float16* __restrict__ X3)
{
    __shared__ _Float16 Wa_s[30 * KP1];     // 30 KB
    __shared__ float prm[4][32];
    __shared__ float phi_s[4][CHARLEN];

    const int t = threadIdx.x;
#pragma unroll
    for (int i = 0; i < 8; i++) {
        const int idx = t + i * 256;
        if (idx < 1920) {
            const int row = idx >> 6;
            const int c8  = (idx & 63) << 3;
            *(half8*)(&Wa_s[row * KP1 + c8]) = *(const half8*)(Wa + (size_t)row * KP1 + c8);
        }
    }
    __syncthreads();

    const int wave = t >> 6;
    const int lane = t & 63;
    const int b = blockIdx.x * 4 + wave;

    half8 xa = *(const half8*)(XA + (size_t)b * KP1 + lane * 8);
    float xf[8];
#pragma unroll
    for (int e = 0; e < 8; e++) xf[e] = (float)xa[e];

    float myp = 0.f;
#pragma unroll
    for (int m = 0; m < 30; m++) {
        half8 wv = *(const half8*)(&Wa_s[m * KP1 + lane * 8]);
        float s = 0.f;
#pragma unroll
        for (int e = 0; e < 8; e++) s += (float)wv[e] * xf[e];
#pragma unroll
        for (int sh = 32; sh >= 1; sh >>= 1) s += __shfl_xor(s, sh, 64);
        if (lane == m) myp = s;
    }

    if (lane < 30) {
        float p  = myp + b_attn[lane];
        float sp = (p > 20.f) ? p : log1pf(expf(p));
        float v;
        if (lane < 10)      v = sp;
        else if (lane < 20) v = fmaxf(sp, 0.01f);
        else                v = kappa[(size_t)b * NATTN + (lane - 20)] + sp * (1.f / 25.f);
        prm[wave][lane] = v;
    }
    __syncthreads();

    const int len = alen[b];
    {
        int c = lane;
        float phi = 0.f;
#pragma unroll
        for (int j = 0; j < NATTN; j++) {
            float d = prm[wave][20 + j] - (float)c;
            phi += prm[wave][j] * expf(-d * d / prm[wave][10 + j]);
        }
        phi_s[wave][c] = (c < len) ? phi : 0.f;
    }
    __syncthreads();

    for (int v0 = 0; v0 < VOCAB; v0 += 64) {
        const int v = v0 + lane;
        if (v < VOCAB) {
            const float* avb = AV + (size_t)b * CHARLEN * VOCAB + v;
            float s = 0.f;
            for (int c = 0; c < len; c++)
                s += phi_s[wave][c] * avb[(size_t)c * VOCAB];
            _Float16 wv = (_Float16)s;
            X2[(size_t)b * KP23 + 403 + v] = wv;
            X3[(size_t)b * KP23 + 403 + v] = wv;
        }
    }
}

// ---------------------------------------------------------------- launch
extern "C" void kernel_launch(void* const* d_in, const int* in_sizes, int n_in,
                              void* d_out, int out_size, void* d_ws, size_t ws_size,
                              hipStream_t stream)
{
    const float* inputs = (const float*)d_in[0];
    const float* h1     = (const float*)d_in[1];
    const float* c1     = (const float*)d_in[2];
    const float* h2     = (const float*)d_in[3];
    const float* c2     = (const float*)d_in[4];
    const float* h3     = (const float*)d_in[5];
    const float* c3     = (const float*)d_in[6];
    const float* kappa  = (const float*)d_in[7];
    const float* w_prev = (const float*)d_in[8];
    const float* AV     = (const float*)d_in[9];
    const int*   alen   = (const int*)d_in[10];
    const float* W_ih1  = (const float*)d_in[11];
    const float* W_hh1  = (const float*)d_in[12];
    const float* b1     = (const float*)d_in[13];
    const float* W_attn = (const float*)d_in[14];
    const float* b_attn = (const float*)d_in[15];
    const float* W_ih2  = (const float*)d_in[16];
    const float* W_hh2  = (const float*)d_in[17];
    const float* b2     = (const float*)d_in[18];
    const float* W_ih3  = (const float*)d_in[19];
    const float* W_hh3  = (const float*)d_in[20];
    const float* b3     = (const float*)d_in[21];
    float* out = (float*)d_out;

    char* p = (char*)d_ws;
    _Float16* X1 = (_Float16*)p; p += (size_t)B_SZ * KP1 * 2;
    _Float16* XA = (_Float16*)p; p += (size_t)B_SZ * KP1 * 2;
    _Float16* X2 = (_Float16*)p; p += (size_t)B_SZ * KP23 * 2;
    _Float16* X3 = (_Float16*)p; p += (size_t)B_SZ * KP23 * 2;
    _Float16* W1 = (_Float16*)p; p += (size_t)NG * KP1 * 2;
    _Float16* W2 = (_Float16*)p; p += (size_t)NG * KP23 * 2;
    _Float16* W3 = (_Float16*)p; p += (size_t)NG * KP23 * 2;
    _Float16* Wa = (_Float16*)p; p += (size_t)64 * KP1 * 2;

    pack_all<<<O7 / 256, 256, 0, stream>>>(W_ih1, W_hh1, W_ih2, W_hh2,
                                           W_ih3, W_hh3, W_attn,
                                           w_prev, inputs, h1, h2, h3,
                                           W1, W2, W3, Wa, X1, XA, X2, X3);

    const dim3 fgrid(16, 25);   // 400 blocks = 8 XCD x 50

    // LSTM1: h1n -> XA col 0 (attn input) + X2 col 0
    gemm_fused_t<KP1><<<fgrid, 512, 0, stream>>>(W1, X1, b1, c1,
                                                 XA, KP1, X2, KP23, nullptr);
    // attention: params (wave-dot GEMM) + phi + einsum -> w into X2, X3
    attn_fused<<<B_SZ / 4, 256, 0, stream>>>(Wa, XA, b_attn, kappa, AV, alen, X2, X3);
    // LSTM2: h2n -> X3 col 0
    gemm_fused_t<KP23><<<fgrid, 512, 0, stream>>>(W2, X2, b2, c2,
                                                  X3, KP23, nullptr, 0, nullptr);
    // LSTM3: h3n -> out (fp32)
    gemm_fused_t<KP23><<<fgrid, 512, 0, stream>>>(W3, X3, b3, c3,
                                                  nullptr, 0, nullptr, 0, out);
}